// Round 5
// baseline (776.829 us; speedup 1.0000x reference)
//
#include <hip/hip_runtime.h>
#include <hip/hip_bf16.h>

// GCN 3-layer forward: out = A_norm( relu( A_norm( relu( A_norm(xW1)+b1 ) W2)+b2 ) W3 ) + b3
// A_norm: symmetric-normalized adjacency with self-loops (d^-1/2 terms), per reference.
//
// Plan per call:
//  1. deg histogram over dst  -> dinv = rsqrt(1+deg)
//  2. exclusive scan -> CSR offsets
//  3. scatter edges sorted by dst, with precomputed w_e = dinv[src]*dinv[dst]
//  4. 3x { fp32 GEMM (W in LDS, 8x8 reg tile) ; per-node wave aggregation + bias (+relu) }
// Feature buffers ping-pong through d_out; ws holds H + CSR.

#define D 128

__global__ void khist(const int* __restrict__ dst, int* __restrict__ deg, int E) {
    int i = blockIdx.x * 256 + threadIdx.x;
    if (i < E) atomicAdd(&deg[dst[i]], 1);
}

__global__ __launch_bounds__(1024) void kscan1(const int* __restrict__ deg,
                                               int* __restrict__ offs,
                                               int* __restrict__ bsums,
                                               float* __restrict__ dinv, int N) {
    __shared__ int s[1024];
    int tid = threadIdx.x;
    int i = blockIdx.x * 1024 + tid;
    int v = (i < N) ? deg[i] : 0;
    s[tid] = v;
    __syncthreads();
    for (int d = 1; d < 1024; d <<= 1) {
        int t = (tid >= d) ? s[tid - d] : 0;
        __syncthreads();
        s[tid] += t;
        __syncthreads();
    }
    if (i < N) {
        offs[i] = s[tid] - v;                 // exclusive
        dinv[i] = rsqrtf(1.0f + (float)v);
    }
    if (tid == 1023) bsums[blockIdx.x] = s[1023];
}

__global__ __launch_bounds__(128) void kscan2(int* bsums, int nb) {
    __shared__ int s[128];
    int tid = threadIdx.x;
    int v = (tid < nb) ? bsums[tid] : 0;
    s[tid] = v;
    __syncthreads();
    for (int d = 1; d < 128; d <<= 1) {
        int t = (tid >= d) ? s[tid - d] : 0;
        __syncthreads();
        s[tid] += t;
        __syncthreads();
    }
    if (tid < nb) bsums[tid] = s[tid] - v;    // exclusive block offsets
}

__global__ void kscan3(int* __restrict__ offs, const int* __restrict__ bsums, int N, int E) {
    int i = blockIdx.x * 256 + threadIdx.x;
    if (i < N) offs[i] += bsums[i >> 10];
    if (i == 0) offs[N] = E;
}

__global__ void kscatter(const int* __restrict__ src, const int* __restrict__ dst,
                         const int* __restrict__ offs, int* __restrict__ cursor,
                         const float* __restrict__ dinv, int2* __restrict__ ew, int E) {
    int i = blockIdx.x * 256 + threadIdx.x;
    if (i >= E) return;
    int s = src[i], d = dst[i];
    int pos = offs[d] + atomicAdd(&cursor[d], 1);
    ew[pos] = make_int2(s, __float_as_int(dinv[s] * dinv[d]));
}

// H[M x 128] = X[M x 128] @ W[128 x 128].  W staged in LDS; 8x8 register tile.
__global__ __launch_bounds__(256) void kgemm(const float* __restrict__ X,
                                             const float* __restrict__ W,
                                             float* __restrict__ H, int M) {
    __shared__ float sW[D * D];
    int tid = threadIdx.x;
#pragma unroll
    for (int i = 0; i < 16; i++)
        ((float4*)sW)[tid + i * 256] = ((const float4*)W)[tid + i * 256];
    __syncthreads();

    int row0 = blockIdx.x * 128;
    int tc = tid & 15;   // 16 col groups * 8 cols
    int tr = tid >> 4;   // 16 row groups * 8 rows

    const float* xbase[8];
#pragma unroll
    for (int r = 0; r < 8; r++) {
        int row = row0 + tr * 8 + r;
        if (row >= M) row = M - 1;           // clamp to avoid OOB reads
        xbase[r] = X + (size_t)row * D;
    }

    float acc[8][8];
#pragma unroll
    for (int r = 0; r < 8; r++)
#pragma unroll
        for (int c = 0; c < 8; c++) acc[r][c] = 0.0f;

    const float* wb = sW + tc * 8;
    for (int k4 = 0; k4 < 32; k4++) {
        float xv[8][4];
#pragma unroll
        for (int r = 0; r < 8; r++) {
            float4 t = ((const float4*)xbase[r])[k4];
            xv[r][0] = t.x; xv[r][1] = t.y; xv[r][2] = t.z; xv[r][3] = t.w;
        }
#pragma unroll
        for (int kk = 0; kk < 4; kk++) {
            int k = k4 * 4 + kk;
            float4 w0 = *(const float4*)(wb + k * D);
            float4 w1 = *(const float4*)(wb + k * D + 4);
            float wv[8] = {w0.x, w0.y, w0.z, w0.w, w1.x, w1.y, w1.z, w1.w};
#pragma unroll
            for (int r = 0; r < 8; r++)
#pragma unroll
                for (int c = 0; c < 8; c++)
                    acc[r][c] = fmaf(xv[r][kk], wv[c], acc[r][c]);
        }
    }

#pragma unroll
    for (int r = 0; r < 8; r++) {
        int row = row0 + tr * 8 + r;
        if (row < M) {
            float4 o0 = {acc[r][0], acc[r][1], acc[r][2], acc[r][3]};
            float4 o1 = {acc[r][4], acc[r][5], acc[r][6], acc[r][7]};
            float4* hp = (float4*)(H + (size_t)row * D + tc * 8);
            hp[0] = o0; hp[1] = o1;
        }
    }
}

// One wave per node: Y_i = [relu]( sum_e w_e * H[src_e] + dinv_i^2 * H_i + b )
__global__ __launch_bounds__(256) void kagg(const float* __restrict__ H,
                                            const int2* __restrict__ ew,
                                            const int* __restrict__ offs,
                                            const float* __restrict__ dinv,
                                            const float* __restrict__ bias,
                                            float* __restrict__ Y, int N, int relu) {
    int wid = blockIdx.x * 4 + (threadIdx.x >> 6);
    int lane = threadIdx.x & 63;
    if (wid >= N) return;
    int beg = offs[wid], end = offs[wid + 1];
    const float2* Hp = (const float2*)H;
    float ax = 0.0f, ay = 0.0f;
    int e = beg;
    for (; e + 4 <= end; e += 4) {
        int2 e0 = ew[e + 0], e1 = ew[e + 1], e2 = ew[e + 2], e3 = ew[e + 3];
        float2 h0 = Hp[(size_t)e0.x * 64 + lane];
        float2 h1 = Hp[(size_t)e1.x * 64 + lane];
        float2 h2 = Hp[(size_t)e2.x * 64 + lane];
        float2 h3 = Hp[(size_t)e3.x * 64 + lane];
        float w0 = __int_as_float(e0.y), w1 = __int_as_float(e1.y);
        float w2 = __int_as_float(e2.y), w3 = __int_as_float(e3.y);
        ax = fmaf(w0, h0.x, ax); ay = fmaf(w0, h0.y, ay);
        ax = fmaf(w1, h1.x, ax); ay = fmaf(w1, h1.y, ay);
        ax = fmaf(w2, h2.x, ax); ay = fmaf(w2, h2.y, ay);
        ax = fmaf(w3, h3.x, ax); ay = fmaf(w3, h3.y, ay);
    }
    for (; e < end; e++) {
        int2 e0 = ew[e];
        float2 h0 = Hp[(size_t)e0.x * 64 + lane];
        float w0 = __int_as_float(e0.y);
        ax = fmaf(w0, h0.x, ax); ay = fmaf(w0, h0.y, ay);
    }
    float di = dinv[wid];
    float d2 = di * di;
    float2 hs = Hp[(size_t)wid * 64 + lane];
    ax = fmaf(d2, hs.x, ax) + bias[lane * 2];
    ay = fmaf(d2, hs.y, ay) + bias[lane * 2 + 1];
    if (relu) { ax = fmaxf(ax, 0.0f); ay = fmaxf(ay, 0.0f); }
    ((float2*)Y)[(size_t)wid * 64 + lane] = make_float2(ax, ay);
}

extern "C" void kernel_launch(void* const* d_in, const int* in_sizes, int n_in,
                              void* d_out, int out_size, void* d_ws, size_t ws_size,
                              hipStream_t stream) {
    const float* x  = (const float*)d_in[0];
    const int*   ei = (const int*)d_in[1];
    const float* W1 = (const float*)d_in[2];
    const float* b1 = (const float*)d_in[3];
    const float* W2 = (const float*)d_in[4];
    const float* b2 = (const float*)d_in[5];
    const float* W3 = (const float*)d_in[6];
    const float* b3 = (const float*)d_in[7];
    float* out = (float*)d_out;

    int N = in_sizes[0] / D;    // 100000
    int E = in_sizes[1] / 2;    // 1600000
    const int* srcp = ei;
    const int* dstp = ei + E;

    // workspace layout (256B aligned)
    char* base = (char*)d_ws;
    size_t off = 0;
    auto alloc = [&](size_t bytes) {
        char* p = base + off;
        off = (off + bytes + 255) & ~(size_t)255;
        return p;
    };
    int*   deg    = (int*)alloc((size_t)N * 4);
    int*   offs   = (int*)alloc((size_t)(N + 1) * 4);
    int*   bsums  = (int*)alloc(256 * 4);
    int*   cursor = (int*)alloc((size_t)N * 4);
    float* dinv   = (float*)alloc((size_t)N * 4);
    int2*  ew     = (int2*)alloc((size_t)E * 8);
    float* H      = (float*)alloc((size_t)N * D * 4);
    (void)ws_size;

    hipMemsetAsync(deg, 0, (size_t)N * 4, stream);
    hipMemsetAsync(cursor, 0, (size_t)N * 4, stream);

    khist<<<dim3((E + 255) / 256), dim3(256), 0, stream>>>(dstp, deg, E);
    int nb = (N + 1023) / 1024;
    kscan1<<<dim3(nb), dim3(1024), 0, stream>>>(deg, offs, bsums, dinv, N);
    kscan2<<<dim3(1), dim3(128), 0, stream>>>(bsums, nb);
    kscan3<<<dim3((N + 255) / 256), dim3(256), 0, stream>>>(offs, bsums, N, E);
    kscatter<<<dim3((E + 255) / 256), dim3(256), 0, stream>>>(srcp, dstp, offs, cursor, dinv, ew, E);

    dim3 gg((N + 127) / 128), gb(256);
    dim3 ag((N + 3) / 4);

    // layer 1: x -> H -> out (relu)
    kgemm<<<gg, gb, 0, stream>>>(x, W1, H, N);
    kagg<<<ag, gb, 0, stream>>>(H, ew, offs, dinv, b1, out, N, 1);
    // layer 2: out -> H -> out (relu)
    kgemm<<<gg, gb, 0, stream>>>(out, W2, H, N);
    kagg<<<ag, gb, 0, stream>>>(H, ew, offs, dinv, b2, out, N, 1);
    // layer 3: out -> H -> out (no relu)
    kgemm<<<gg, gb, 0, stream>>>(out, W3, H, N);
    kagg<<<ag, gb, 0, stream>>>(H, ew, offs, dinv, b3, out, N, 0);
}

// Round 6
// 639.497 us; speedup vs baseline: 1.2147x; 1.2147x over previous
//
#include <hip/hip_runtime.h>
#include <hip/hip_bf16.h>
#include <hip/hip_fp16.h>

// GCN 3-layer forward. CSR build once, then 3x { fp32 GEMM -> fp16 H ; gather-agg }.
// H stored fp16 (25.6MB): halves the random-gather traffic that dominated round 5
// (kagg FETCH_SIZE 405MB @ 3.87TB/s, 49% L2 hit). Accumulation stays fp32.

#define D 128

__global__ void khist(const int* __restrict__ dst, int* __restrict__ deg, int E) {
    int i = blockIdx.x * 256 + threadIdx.x;
    if (i < E) atomicAdd(&deg[dst[i]], 1);
}

__global__ __launch_bounds__(1024) void kscan1(const int* __restrict__ deg,
                                               int* __restrict__ offs,
                                               int* __restrict__ bsums,
                                               float* __restrict__ dinv, int N) {
    __shared__ int s[1024];
    int tid = threadIdx.x;
    int i = blockIdx.x * 1024 + tid;
    int v = (i < N) ? deg[i] : 0;
    s[tid] = v;
    __syncthreads();
    for (int d = 1; d < 1024; d <<= 1) {
        int t = (tid >= d) ? s[tid - d] : 0;
        __syncthreads();
        s[tid] += t;
        __syncthreads();
    }
    if (i < N) {
        offs[i] = s[tid] - v;                 // exclusive
        dinv[i] = rsqrtf(1.0f + (float)v);
    }
    if (tid == 1023) bsums[blockIdx.x] = s[1023];
}

__global__ __launch_bounds__(128) void kscan2(int* bsums, int nb) {
    __shared__ int s[128];
    int tid = threadIdx.x;
    int v = (tid < nb) ? bsums[tid] : 0;
    s[tid] = v;
    __syncthreads();
    for (int d = 1; d < 128; d <<= 1) {
        int t = (tid >= d) ? s[tid - d] : 0;
        __syncthreads();
        s[tid] += t;
        __syncthreads();
    }
    if (tid < nb) bsums[tid] = s[tid] - v;    // exclusive block offsets
}

__global__ void kscan3(int* __restrict__ offs, const int* __restrict__ bsums, int N, int E) {
    int i = blockIdx.x * 256 + threadIdx.x;
    if (i < N) offs[i] += bsums[i >> 10];
    if (i == 0) offs[N] = E;
}

__global__ void kscatter(const int* __restrict__ src, const int* __restrict__ dst,
                         const int* __restrict__ offs, int* __restrict__ cursor,
                         const float* __restrict__ dinv, int2* __restrict__ ew, int E) {
    int i = blockIdx.x * 256 + threadIdx.x;
    if (i >= E) return;
    int s = src[i], d = dst[i];
    int pos = offs[d] + atomicAdd(&cursor[d], 1);
    ew[pos] = make_int2(s, __float_as_int(dinv[s] * dinv[d]));
}

// H[M x 128] (fp16) = X[M x 128] (fp32) @ W[128 x 128].  W in LDS; 8x8 reg tile.
__global__ __launch_bounds__(256) void kgemm(const float* __restrict__ X,
                                             const float* __restrict__ W,
                                             __half* __restrict__ H, int M) {
    __shared__ float sW[D * D];
    int tid = threadIdx.x;
#pragma unroll
    for (int i = 0; i < 16; i++)
        ((float4*)sW)[tid + i * 256] = ((const float4*)W)[tid + i * 256];
    __syncthreads();

    int row0 = blockIdx.x * 128;
    int tc = tid & 15;   // 16 col groups * 8 cols
    int tr = tid >> 4;   // 16 row groups * 8 rows

    const float* xbase[8];
#pragma unroll
    for (int r = 0; r < 8; r++) {
        int row = row0 + tr * 8 + r;
        if (row >= M) row = M - 1;           // clamp to avoid OOB reads
        xbase[r] = X + (size_t)row * D;
    }

    float acc[8][8];
#pragma unroll
    for (int r = 0; r < 8; r++)
#pragma unroll
        for (int c = 0; c < 8; c++) acc[r][c] = 0.0f;

    const float* wb = sW + tc * 8;
    for (int k4 = 0; k4 < 32; k4++) {
        float xv[8][4];
#pragma unroll
        for (int r = 0; r < 8; r++) {
            float4 t = ((const float4*)xbase[r])[k4];
            xv[r][0] = t.x; xv[r][1] = t.y; xv[r][2] = t.z; xv[r][3] = t.w;
        }
#pragma unroll
        for (int kk = 0; kk < 4; kk++) {
            int k = k4 * 4 + kk;
            float4 w0 = *(const float4*)(wb + k * D);
            float4 w1 = *(const float4*)(wb + k * D + 4);
            float wv[8] = {w0.x, w0.y, w0.z, w0.w, w1.x, w1.y, w1.z, w1.w};
#pragma unroll
            for (int r = 0; r < 8; r++)
#pragma unroll
                for (int c = 0; c < 8; c++)
                    acc[r][c] = fmaf(xv[r][kk], wv[c], acc[r][c]);
        }
    }

#pragma unroll
    for (int r = 0; r < 8; r++) {
        int row = row0 + tr * 8 + r;
        if (row < M) {
            union { __half2 h[4]; float4 f; } u;
            u.h[0] = __floats2half2_rn(acc[r][0], acc[r][1]);
            u.h[1] = __floats2half2_rn(acc[r][2], acc[r][3]);
            u.h[2] = __floats2half2_rn(acc[r][4], acc[r][5]);
            u.h[3] = __floats2half2_rn(acc[r][6], acc[r][7]);
            *(float4*)(H + (size_t)row * D + tc * 8) = u.f;   // 16B aligned
        }
    }
}

// One wave per node: Y_i = [relu]( sum_e w_e * H[src_e] + dinv_i^2 * H_i + b )
// H is fp16 (half2 per lane = 256B per row gather); fp32 accumulation.
__global__ __launch_bounds__(256) void kagg(const __half* __restrict__ H,
                                            const int2* __restrict__ ew,
                                            const int* __restrict__ offs,
                                            const float* __restrict__ dinv,
                                            const float* __restrict__ bias,
                                            float* __restrict__ Y, int N, int relu) {
    int wid = blockIdx.x * 4 + (threadIdx.x >> 6);
    int lane = threadIdx.x & 63;
    if (wid >= N) return;
    int beg = offs[wid], end = offs[wid + 1];
    const __half2* Hp = (const __half2*)H;   // 64 half2 per row
    float ax = 0.0f, ay = 0.0f;
    int e = beg;
    for (; e + 8 <= end; e += 8) {
        int2 ee[8];
#pragma unroll
        for (int u = 0; u < 8; u++) ee[u] = ew[e + u];
        __half2 hr[8];
#pragma unroll
        for (int u = 0; u < 8; u++) hr[u] = Hp[(size_t)ee[u].x * 64 + lane];
#pragma unroll
        for (int u = 0; u < 8; u++) {
            float w = __int_as_float(ee[u].y);
            float2 f = __half22float2(hr[u]);
            ax = fmaf(w, f.x, ax); ay = fmaf(w, f.y, ay);
        }
    }
    for (; e < end; e++) {
        int2 e0 = ew[e];
        float2 f = __half22float2(Hp[(size_t)e0.x * 64 + lane]);
        float w0 = __int_as_float(e0.y);
        ax = fmaf(w0, f.x, ax); ay = fmaf(w0, f.y, ay);
    }
    float di = dinv[wid];
    float d2 = di * di;
    float2 hs = __half22float2(Hp[(size_t)wid * 64 + lane]);
    float2 bv = ((const float2*)bias)[lane];
    ax = fmaf(d2, hs.x, ax) + bv.x;
    ay = fmaf(d2, hs.y, ay) + bv.y;
    if (relu) { ax = fmaxf(ax, 0.0f); ay = fmaxf(ay, 0.0f); }
    ((float2*)Y)[(size_t)wid * 64 + lane] = make_float2(ax, ay);
}

extern "C" void kernel_launch(void* const* d_in, const int* in_sizes, int n_in,
                              void* d_out, int out_size, void* d_ws, size_t ws_size,
                              hipStream_t stream) {
    const float* x  = (const float*)d_in[0];
    const int*   ei = (const int*)d_in[1];
    const float* W1 = (const float*)d_in[2];
    const float* b1 = (const float*)d_in[3];
    const float* W2 = (const float*)d_in[4];
    const float* b2 = (const float*)d_in[5];
    const float* W3 = (const float*)d_in[6];
    const float* b3 = (const float*)d_in[7];
    float* out = (float*)d_out;

    int N = in_sizes[0] / D;    // 100000
    int E = in_sizes[1] / 2;    // 1600000
    const int* srcp = ei;
    const int* dstp = ei + E;

    // workspace layout (256B aligned)
    char* base = (char*)d_ws;
    size_t off = 0;
    auto alloc = [&](size_t bytes) {
        char* p = base + off;
        off = (off + bytes + 255) & ~(size_t)255;
        return p;
    };
    int*    deg    = (int*)alloc((size_t)N * 4);
    int*    offs   = (int*)alloc((size_t)(N + 1) * 4);
    int*    bsums  = (int*)alloc(256 * 4);
    int*    cursor = (int*)alloc((size_t)N * 4);
    float*  dinv   = (float*)alloc((size_t)N * 4);
    int2*   ew     = (int2*)alloc((size_t)E * 8);
    __half* H      = (__half*)alloc((size_t)N * D * 2);
    (void)ws_size;

    hipMemsetAsync(deg, 0, (size_t)N * 4, stream);
    hipMemsetAsync(cursor, 0, (size_t)N * 4, stream);

    khist<<<dim3((E + 255) / 256), dim3(256), 0, stream>>>(dstp, deg, E);
    int nb = (N + 1023) / 1024;
    kscan1<<<dim3(nb), dim3(1024), 0, stream>>>(deg, offs, bsums, dinv, N);
    kscan2<<<dim3(1), dim3(128), 0, stream>>>(bsums, nb);
    kscan3<<<dim3((N + 255) / 256), dim3(256), 0, stream>>>(offs, bsums, N, E);
    kscatter<<<dim3((E + 255) / 256), dim3(256), 0, stream>>>(srcp, dstp, offs, cursor, dinv, ew, E);

    dim3 gg((N + 127) / 128), gb(256);
    dim3 ag((N + 3) / 4);

    // layer 1: x -> H(fp16) -> out (relu)
    kgemm<<<gg, gb, 0, stream>>>(x, W1, H, N);
    kagg<<<ag, gb, 0, stream>>>(H, ew, offs, dinv, b1, out, N, 1);
    // layer 2: out -> H -> out (relu)
    kgemm<<<gg, gb, 0, stream>>>(out, W2, H, N);
    kagg<<<ag, gb, 0, stream>>>(H, ew, offs, dinv, b2, out, N, 1);
    // layer 3: out -> H -> out (no relu)
    kgemm<<<gg, gb, 0, stream>>>(out, W3, H, N);
    kagg<<<ag, gb, 0, stream>>>(H, ew, offs, dinv, b3, out, N, 0);
}

// Round 8
// 545.144 us; speedup vs baseline: 1.4250x; 1.1731x over previous
//
#include <hip/hip_runtime.h>
#include <hip/hip_bf16.h>
#include <hip/hip_fp16.h>

// GCN 3-layer forward. CSR build once, then 3x { MFMA fp16 GEMM -> fp16 H ; gather-agg }.
// R5: kagg was 405MB FETCH @3.87TB/s -> fp16 H halved it (R6: 195MB, 81.6us).
// R7: kgemm fp32 VALU (~50-70us est) -> mfma_f32_16x16x32_f16, memory-bound ~15us.

#define D 128

typedef _Float16 f16x8 __attribute__((ext_vector_type(8)));
typedef float f32x4 __attribute__((ext_vector_type(4)));

__global__ void khist(const int* __restrict__ dst, int* __restrict__ deg, int E) {
    int i = blockIdx.x * 256 + threadIdx.x;
    if (i < E) atomicAdd(&deg[dst[i]], 1);
}

__global__ __launch_bounds__(1024) void kscan1(const int* __restrict__ deg,
                                               int* __restrict__ offs,
                                               int* __restrict__ bsums,
                                               float* __restrict__ dinv, int N) {
    __shared__ int s[1024];
    int tid = threadIdx.x;
    int i = blockIdx.x * 1024 + tid;
    int v = (i < N) ? deg[i] : 0;
    s[tid] = v;
    __syncthreads();
    for (int d = 1; d < 1024; d <<= 1) {
        int t = (tid >= d) ? s[tid - d] : 0;
        __syncthreads();
        s[tid] += t;
        __syncthreads();
    }
    if (i < N) {
        offs[i] = s[tid] - v;                 // exclusive
        dinv[i] = rsqrtf(1.0f + (float)v);
    }
    if (tid == 1023) bsums[blockIdx.x] = s[1023];
}

__global__ __launch_bounds__(128) void kscan2(int* bsums, int nb) {
    __shared__ int s[128];
    int tid = threadIdx.x;
    int v = (tid < nb) ? bsums[tid] : 0;
    s[tid] = v;
    __syncthreads();
    for (int d = 1; d < 128; d <<= 1) {
        int t = (tid >= d) ? s[tid - d] : 0;
        __syncthreads();
        s[tid] += t;
        __syncthreads();
    }
    if (tid < nb) bsums[tid] = s[tid] - v;    // exclusive block offsets
}

__global__ void kscan3(int* __restrict__ offs, const int* __restrict__ bsums, int N, int E) {
    int i = blockIdx.x * 256 + threadIdx.x;
    if (i < N) offs[i] += bsums[i >> 10];
    if (i == 0) offs[N] = E;
}

__global__ void kscatter(const int* __restrict__ src, const int* __restrict__ dst,
                         const int* __restrict__ offs, int* __restrict__ cursor,
                         const float* __restrict__ dinv, int2* __restrict__ ew, int E) {
    int i = blockIdx.x * 256 + threadIdx.x;
    if (i >= E) return;
    int s = src[i], d = dst[i];
    int pos = offs[d] + atomicAdd(&cursor[d], 1);
    ew[pos] = make_int2(s, __float_as_int(dinv[s] * dinv[d]));
}

// H[M x 128] (fp16) = X[M x 128] (fp32) @ W[128 x 128] via mfma_f32_16x16x32_f16.
// Block: 512 thr = 8 waves, 128 rows (16 rows/wave). W^T fp16 in LDS, row pad 136.
// Layouts (gfx950, m89-verified C/D; standard A/B): A: m=l&15, k=8*(l>>4)+j;
// B: n=l&15, k=8*(l>>4)+j; D: n=l&15, m=(l>>4)*4+reg.
__global__ __launch_bounds__(512) void kgemm_mfma(const float* __restrict__ X,
                                                  const float* __restrict__ W,
                                                  __half* __restrict__ H, int M) {
    __shared__ _Float16 sWT[D * 136];
    int tid = threadIdx.x;
    for (int idx = tid; idx < D * D; idx += 512) {
        int k = idx >> 7, n = idx & 127;
        sWT[n * 136 + k] = (_Float16)W[idx];
    }
    __syncthreads();

    int w  = tid >> 6;       // wave 0..7
    int l  = tid & 63;
    int lr = l & 15;         // A row / B,D col within tile
    int lq = l >> 4;         // k-chunk (A,B) / row-quad (D)
    int rowbase = blockIdx.x * 128 + w * 16;

    int arow = rowbase + lr;
    if (arow >= M) arow = M - 1;             // clamp OOB loads
    const float* xr = X + (size_t)arow * D;

    f16x8 afrag[4];
#pragma unroll
    for (int kt = 0; kt < 4; kt++) {
        const float4* xp = (const float4*)(xr + kt * 32 + 8 * lq);
        float4 t0 = xp[0], t1 = xp[1];
        f16x8 a;
        a[0] = (_Float16)t0.x; a[1] = (_Float16)t0.y;
        a[2] = (_Float16)t0.z; a[3] = (_Float16)t0.w;
        a[4] = (_Float16)t1.x; a[5] = (_Float16)t1.y;
        a[6] = (_Float16)t1.z; a[7] = (_Float16)t1.w;
        afrag[kt] = a;
    }

    _Float16* Hh = (_Float16*)H;
#pragma unroll
    for (int ct = 0; ct < 8; ct++) {
        f32x4 acc = {0.f, 0.f, 0.f, 0.f};
#pragma unroll
        for (int kt = 0; kt < 4; kt++) {
            f16x8 b = *(const f16x8*)(&sWT[(ct * 16 + lr) * 136 + kt * 32 + 8 * lq]);
            acc = __builtin_amdgcn_mfma_f32_16x16x32_f16(afrag[kt], b, acc, 0, 0, 0);
        }
        int col = ct * 16 + lr;
#pragma unroll
        for (int i = 0; i < 4; i++) {
            int rd = rowbase + lq * 4 + i;
            if (rd < M) Hh[(size_t)rd * D + col] = (_Float16)acc[i];
        }
    }
}

// One wave per node: Y_i = [relu]( sum_e w_e * H[src_e] + dinv_i^2 * H_i + b )
// H is fp16 (half2 per lane = 256B per row gather); fp32 accumulation.
__global__ __launch_bounds__(256) void kagg(const __half* __restrict__ H,
                                            const int2* __restrict__ ew,
                                            const int* __restrict__ offs,
                                            const float* __restrict__ dinv,
                                            const float* __restrict__ bias,
                                            float* __restrict__ Y, int N, int relu) {
    int wid = blockIdx.x * 4 + (threadIdx.x >> 6);
    int lane = threadIdx.x & 63;
    if (wid >= N) return;
    int beg = offs[wid], end = offs[wid + 1];
    const __half2* Hp = (const __half2*)H;   // 64 half2 per row
    float ax = 0.0f, ay = 0.0f;
    int e = beg;
    for (; e + 8 <= end; e += 8) {
        int2 ee[8];
#pragma unroll
        for (int u = 0; u < 8; u++) ee[u] = ew[e + u];
        __half2 hr[8];
#pragma unroll
        for (int u = 0; u < 8; u++) hr[u] = Hp[(size_t)ee[u].x * 64 + lane];
#pragma unroll
        for (int u = 0; u < 8; u++) {
            float w = __int_as_float(ee[u].y);
            float2 f = __half22float2(hr[u]);
            ax = fmaf(w, f.x, ax); ay = fmaf(w, f.y, ay);
        }
    }
    for (; e < end; e++) {
        int2 e0 = ew[e];
        float2 f = __half22float2(Hp[(size_t)e0.x * 64 + lane]);
        float w0 = __int_as_float(e0.y);
        ax = fmaf(w0, f.x, ax); ay = fmaf(w0, f.y, ay);
    }
    float di = dinv[wid];
    float d2 = di * di;
    float2 hs = __half22float2(Hp[(size_t)wid * 64 + lane]);
    float2 bv = ((const float2*)bias)[lane];
    ax = fmaf(d2, hs.x, ax) + bv.x;
    ay = fmaf(d2, hs.y, ay) + bv.y;
    if (relu) { ax = fmaxf(ax, 0.0f); ay = fmaxf(ay, 0.0f); }
    ((float2*)Y)[(size_t)wid * 64 + lane] = make_float2(ax, ay);
}

extern "C" void kernel_launch(void* const* d_in, const int* in_sizes, int n_in,
                              void* d_out, int out_size, void* d_ws, size_t ws_size,
                              hipStream_t stream) {
    const float* x  = (const float*)d_in[0];
    const int*   ei = (const int*)d_in[1];
    const float* W1 = (const float*)d_in[2];
    const float* b1 = (const float*)d_in[3];
    const float* W2 = (const float*)d_in[4];
    const float* b2 = (const float*)d_in[5];
    const float* W3 = (const float*)d_in[6];
    const float* b3 = (const float*)d_in[7];
    float* out = (float*)d_out;

    int N = in_sizes[0] / D;    // 100000
    int E = in_sizes[1] / 2;    // 1600000
    const int* srcp = ei;
    const int* dstp = ei + E;

    // workspace layout (256B aligned)
    char* base = (char*)d_ws;
    size_t off = 0;
    auto alloc = [&](size_t bytes) {
        char* p = base + off;
        off = (off + bytes + 255) & ~(size_t)255;
        return p;
    };
    int*    deg    = (int*)alloc((size_t)N * 4);
    int*    offs   = (int*)alloc((size_t)(N + 1) * 4);
    int*    bsums  = (int*)alloc(256 * 4);
    int*    cursor = (int*)alloc((size_t)N * 4);
    float*  dinv   = (float*)alloc((size_t)N * 4);
    int2*   ew     = (int2*)alloc((size_t)E * 8);
    __half* H      = (__half*)alloc((size_t)N * D * 2);
    (void)ws_size;

    hipMemsetAsync(deg, 0, (size_t)N * 4, stream);
    hipMemsetAsync(cursor, 0, (size_t)N * 4, stream);

    khist<<<dim3((E + 255) / 256), dim3(256), 0, stream>>>(dstp, deg, E);
    int nb = (N + 1023) / 1024;
    kscan1<<<dim3(nb), dim3(1024), 0, stream>>>(deg, offs, bsums, dinv, N);
    kscan2<<<dim3(1), dim3(128), 0, stream>>>(bsums, nb);
    kscan3<<<dim3((N + 255) / 256), dim3(256), 0, stream>>>(offs, bsums, N, E);
    kscatter<<<dim3((E + 255) / 256), dim3(256), 0, stream>>>(srcp, dstp, offs, cursor, dinv, ew, E);

    dim3 gg((N + 127) / 128), gb(512);
    dim3 ag((N + 3) / 4), ab(256);

    // layer 1: x -> H(fp16) -> out (relu)
    kgemm_mfma<<<gg, gb, 0, stream>>>(x, W1, H, N);
    kagg<<<ag, ab, 0, stream>>>(H, ew, offs, dinv, b1, out, N, 1);
    // layer 2: out -> H -> out (relu)
    kgemm_mfma<<<gg, gb, 0, stream>>>(out, W2, H, N);
    kagg<<<ag, ab, 0, stream>>>(H, ew, offs, dinv, b2, out, N, 1);
    // layer 3: out -> H -> out (no relu)
    kgemm_mfma<<<gg, gb, 0, stream>>>(out, W3, H, N);
    kagg<<<ag, ab, 0, stream>>>(H, ew, offs, dinv, b3, out, N, 0);
}

// Round 10
// 476.692 us; speedup vs baseline: 1.6296x; 1.1436x over previous
//
#include <hip/hip_runtime.h>
#include <hip/hip_fp16.h>

// GCN 3-layer forward. CSR build once, then 3x { MFMA fp16 GEMM -> fp16 H ; gather-agg }.
// R6: fp16 H halved gather traffic (kagg 120->81us). R8: MFMA GEMM (639->545us).
// R9: (1) rank-trick scatter (no cursor atomics), (2) fp16 intermediate activations,
//     (3) layer-2 kagg processes 2 nodes/wave as a within-run ILP A/B.

#define D 128

typedef _Float16 f16x8 __attribute__((ext_vector_type(8)));
typedef float f32x4 __attribute__((ext_vector_type(4)));

// deg histogram; rank[i] = arrival order of edge i within its dst bucket (free from atomicAdd)
__global__ void khist(const int* __restrict__ dst, int* __restrict__ deg,
                      int* __restrict__ rank, int E) {
    int i = blockIdx.x * 256 + threadIdx.x;
    if (i < E) rank[i] = atomicAdd(&deg[dst[i]], 1);
}

__global__ __launch_bounds__(1024) void kscan1(const int* __restrict__ deg,
                                               int* __restrict__ offs,
                                               int* __restrict__ bsums,
                                               float* __restrict__ dinv, int N) {
    __shared__ int s[1024];
    int tid = threadIdx.x;
    int i = blockIdx.x * 1024 + tid;
    int v = (i < N) ? deg[i] : 0;
    s[tid] = v;
    __syncthreads();
    for (int d = 1; d < 1024; d <<= 1) {
        int t = (tid >= d) ? s[tid - d] : 0;
        __syncthreads();
        s[tid] += t;
        __syncthreads();
    }
    if (i < N) {
        offs[i] = s[tid] - v;                 // exclusive
        dinv[i] = rsqrtf(1.0f + (float)v);
    }
    if (tid == 1023) bsums[blockIdx.x] = s[1023];
}

__global__ __launch_bounds__(128) void kscan2(int* bsums, int nb) {
    __shared__ int s[128];
    int tid = threadIdx.x;
    int v = (tid < nb) ? bsums[tid] : 0;
    s[tid] = v;
    __syncthreads();
    for (int d = 1; d < 128; d <<= 1) {
        int t = (tid >= d) ? s[tid - d] : 0;
        __syncthreads();
        s[tid] += t;
        __syncthreads();
    }
    if (tid < nb) bsums[tid] = s[tid] - v;    // exclusive block offsets
}

__global__ void kscan3(int* __restrict__ offs, const int* __restrict__ bsums, int N, int E) {
    int i = blockIdx.x * 256 + threadIdx.x;
    if (i < N) offs[i] += bsums[i >> 10];
    if (i == 0) offs[N] = E;
}

// pure computed-position scatter: pos = offs[dst] + rank  (no atomics)
__global__ void kscatter(const int* __restrict__ src, const int* __restrict__ dst,
                         const int* __restrict__ rank, const int* __restrict__ offs,
                         const float* __restrict__ dinv, int2* __restrict__ ew, int E) {
    int i = blockIdx.x * 256 + threadIdx.x;
    if (i >= E) return;
    int s = src[i], d = dst[i];
    ew[offs[d] + rank[i]] = make_int2(s, __float_as_int(dinv[s] * dinv[d]));
}

// H[M x 128] (fp16) = X[M x 128] @ W[128 x 128] via mfma_f32_16x16x32_f16.
// X fp32 (layer 1) or fp16 (layers 2,3). 512 thr = 8 waves, 128 rows/block.
// Layouts (gfx950, m89-verified C/D): A: m=l&15, k=8*(l>>4)+j; B: n=l&15, k=8*(l>>4)+j;
// D: n=l&15, m=(l>>4)*4+reg.
template<bool IN_HALF>
__global__ __launch_bounds__(512) void kgemm_mfma(const void* __restrict__ Xv,
                                                  const float* __restrict__ W,
                                                  _Float16* __restrict__ H, int M) {
    __shared__ _Float16 sWT[D * 136];
    int tid = threadIdx.x;
    for (int idx = tid; idx < D * D; idx += 512) {
        int k = idx >> 7, n = idx & 127;
        sWT[n * 136 + k] = (_Float16)W[idx];
    }
    __syncthreads();

    int w  = tid >> 6;       // wave 0..7
    int l  = tid & 63;
    int lr = l & 15;         // A row / B,D col within tile
    int lq = l >> 4;         // k-chunk (A,B) / row-quad (D)
    int rowbase = blockIdx.x * 128 + w * 16;

    int arow = rowbase + lr;
    if (arow >= M) arow = M - 1;             // clamp OOB loads

    f16x8 afrag[4];
    if constexpr (IN_HALF) {
        const _Float16* xr = (const _Float16*)Xv + (size_t)arow * D;
#pragma unroll
        for (int kt = 0; kt < 4; kt++)
            afrag[kt] = *(const f16x8*)(xr + kt * 32 + 8 * lq);
    } else {
        const float* xr = (const float*)Xv + (size_t)arow * D;
#pragma unroll
        for (int kt = 0; kt < 4; kt++) {
            const float4* xp = (const float4*)(xr + kt * 32 + 8 * lq);
            float4 t0 = xp[0], t1 = xp[1];
            f16x8 a;
            a[0] = (_Float16)t0.x; a[1] = (_Float16)t0.y;
            a[2] = (_Float16)t0.z; a[3] = (_Float16)t0.w;
            a[4] = (_Float16)t1.x; a[5] = (_Float16)t1.y;
            a[6] = (_Float16)t1.z; a[7] = (_Float16)t1.w;
            afrag[kt] = a;
        }
    }

#pragma unroll
    for (int ct = 0; ct < 8; ct++) {
        f32x4 acc = {0.f, 0.f, 0.f, 0.f};
#pragma unroll
        for (int kt = 0; kt < 4; kt++) {
            f16x8 b = *(const f16x8*)(&sWT[(ct * 16 + lr) * 136 + kt * 32 + 8 * lq]);
            acc = __builtin_amdgcn_mfma_f32_16x16x32_f16(afrag[kt], b, acc, 0, 0, 0);
        }
        int col = ct * 16 + lr;
#pragma unroll
        for (int i = 0; i < 4; i++) {
            int rd = rowbase + lq * 4 + i;
            if (rd < M) H[(size_t)rd * D + col] = (_Float16)acc[i];
        }
    }
}

// One wave per node: Y_i = [relu]( sum_e w_e * H[src_e] + dinv_i^2 * H_i + b )
template<bool HALF_OUT>
__global__ __launch_bounds__(256) void kagg1(const __half* __restrict__ H,
                                             const int2* __restrict__ ew,
                                             const int* __restrict__ offs,
                                             const float* __restrict__ dinv,
                                             const float* __restrict__ bias,
                                             void* __restrict__ Y, int N, int relu) {
    int wid = blockIdx.x * 4 + (threadIdx.x >> 6);
    int lane = threadIdx.x & 63;
    if (wid >= N) return;
    int beg = offs[wid], end = offs[wid + 1];
    const __half2* Hp = (const __half2*)H;   // 64 half2 per row
    float ax = 0.0f, ay = 0.0f;
    int e = beg;
    for (; e + 8 <= end; e += 8) {
        int2 ee[8];
#pragma unroll
        for (int u = 0; u < 8; u++) ee[u] = ew[e + u];
        __half2 hr[8];
#pragma unroll
        for (int u = 0; u < 8; u++) hr[u] = Hp[(size_t)ee[u].x * 64 + lane];
#pragma unroll
        for (int u = 0; u < 8; u++) {
            float w = __int_as_float(ee[u].y);
            float2 f = __half22float2(hr[u]);
            ax = fmaf(w, f.x, ax); ay = fmaf(w, f.y, ay);
        }
    }
    for (; e < end; e++) {
        int2 e0 = ew[e];
        float2 f = __half22float2(Hp[(size_t)e0.x * 64 + lane]);
        float w0 = __int_as_float(e0.y);
        ax = fmaf(w0, f.x, ax); ay = fmaf(w0, f.y, ay);
    }
    float di = dinv[wid];
    float d2 = di * di;
    float2 hs = __half22float2(Hp[(size_t)wid * 64 + lane]);
    float2 bv = ((const float2*)bias)[lane];
    ax = fmaf(d2, hs.x, ax) + bv.x;
    ay = fmaf(d2, hs.y, ay) + bv.y;
    if (relu) { ax = fmaxf(ax, 0.0f); ay = fmaxf(ay, 0.0f); }
    if constexpr (HALF_OUT)
        ((__half2*)Y)[(size_t)wid * 64 + lane] = __floats2half2_rn(ax, ay);
    else
        ((float2*)Y)[(size_t)wid * 64 + lane] = make_float2(ax, ay);
}

// Two nodes per wave: doubled independent gather streams (latency-hiding A/B probe).
template<bool HALF_OUT>
__global__ __launch_bounds__(256) void kagg2(const __half* __restrict__ H,
                                             const int2* __restrict__ ew,
                                             const int* __restrict__ offs,
                                             const float* __restrict__ dinv,
                                             const float* __restrict__ bias,
                                             void* __restrict__ Y, int N, int relu) {
    int wv = blockIdx.x * 4 + (threadIdx.x >> 6);
    int lane = threadIdx.x & 63;
    int n0 = wv * 2, n1 = n0 + 1;
    if (n0 >= N) return;
    bool has1 = (n1 < N);
    int b0 = offs[n0], e0 = offs[n0 + 1];
    int b1 = has1 ? offs[n1] : 0, e1 = has1 ? offs[n1 + 1] : 0;
    const __half2* Hp = (const __half2*)H;
    float a0x = 0.f, a0y = 0.f, a1x = 0.f, a1y = 0.f;

    while (b0 + 4 <= e0 && b1 + 4 <= e1) {
        int2 p[4], q[4];
#pragma unroll
        for (int u = 0; u < 4; u++) { p[u] = ew[b0 + u]; q[u] = ew[b1 + u]; }
        __half2 hp[4], hq[4];
#pragma unroll
        for (int u = 0; u < 4; u++) {
            hp[u] = Hp[(size_t)p[u].x * 64 + lane];
            hq[u] = Hp[(size_t)q[u].x * 64 + lane];
        }
#pragma unroll
        for (int u = 0; u < 4; u++) {
            float w0 = __int_as_float(p[u].y); float2 f0 = __half22float2(hp[u]);
            a0x = fmaf(w0, f0.x, a0x); a0y = fmaf(w0, f0.y, a0y);
            float w1 = __int_as_float(q[u].y); float2 f1 = __half22float2(hq[u]);
            a1x = fmaf(w1, f1.x, a1x); a1y = fmaf(w1, f1.y, a1y);
        }
        b0 += 4; b1 += 4;
    }
    for (; b0 + 4 <= e0; b0 += 4) {
        int2 p[4];
#pragma unroll
        for (int u = 0; u < 4; u++) p[u] = ew[b0 + u];
        __half2 hp[4];
#pragma unroll
        for (int u = 0; u < 4; u++) hp[u] = Hp[(size_t)p[u].x * 64 + lane];
#pragma unroll
        for (int u = 0; u < 4; u++) {
            float w = __int_as_float(p[u].y); float2 f = __half22float2(hp[u]);
            a0x = fmaf(w, f.x, a0x); a0y = fmaf(w, f.y, a0y);
        }
    }
    for (; b0 < e0; b0++) {
        int2 p = ew[b0];
        float w = __int_as_float(p.y); float2 f = __half22float2(Hp[(size_t)p.x * 64 + lane]);
        a0x = fmaf(w, f.x, a0x); a0y = fmaf(w, f.y, a0y);
    }
    for (; b1 + 4 <= e1; b1 += 4) {
        int2 q[4];
#pragma unroll
        for (int u = 0; u < 4; u++) q[u] = ew[b1 + u];
        __half2 hq[4];
#pragma unroll
        for (int u = 0; u < 4; u++) hq[u] = Hp[(size_t)q[u].x * 64 + lane];
#pragma unroll
        for (int u = 0; u < 4; u++) {
            float w = __int_as_float(q[u].y); float2 f = __half22float2(hq[u]);
            a1x = fmaf(w, f.x, a1x); a1y = fmaf(w, f.y, a1y);
        }
    }
    for (; b1 < e1; b1++) {
        int2 q = ew[b1];
        float w = __int_as_float(q.y); float2 f = __half22float2(Hp[(size_t)q.x * 64 + lane]);
        a1x = fmaf(w, f.x, a1x); a1y = fmaf(w, f.y, a1y);
    }

    float2 bv = ((const float2*)bias)[lane];
    {
        float di = dinv[n0]; float d2 = di * di;
        float2 hs = __half22float2(Hp[(size_t)n0 * 64 + lane]);
        float ox = fmaf(d2, hs.x, a0x) + bv.x;
        float oy = fmaf(d2, hs.y, a0y) + bv.y;
        if (relu) { ox = fmaxf(ox, 0.f); oy = fmaxf(oy, 0.f); }
        if constexpr (HALF_OUT)
            ((__half2*)Y)[(size_t)n0 * 64 + lane] = __floats2half2_rn(ox, oy);
        else
            ((float2*)Y)[(size_t)n0 * 64 + lane] = make_float2(ox, oy);
    }
    if (has1) {
        float di = dinv[n1]; float d2 = di * di;
        float2 hs = __half22float2(Hp[(size_t)n1 * 64 + lane]);
        float ox = fmaf(d2, hs.x, a1x) + bv.x;
        float oy = fmaf(d2, hs.y, a1y) + bv.y;
        if (relu) { ox = fmaxf(ox, 0.f); oy = fmaxf(oy, 0.f); }
        if constexpr (HALF_OUT)
            ((__half2*)Y)[(size_t)n1 * 64 + lane] = __floats2half2_rn(ox, oy);
        else
            ((float2*)Y)[(size_t)n1 * 64 + lane] = make_float2(ox, oy);
    }
}

extern "C" void kernel_launch(void* const* d_in, const int* in_sizes, int n_in,
                              void* d_out, int out_size, void* d_ws, size_t ws_size,
                              hipStream_t stream) {
    const float* x  = (const float*)d_in[0];
    const int*   ei = (const int*)d_in[1];
    const float* W1 = (const float*)d_in[2];
    const float* b1 = (const float*)d_in[3];
    const float* W2 = (const float*)d_in[4];
    const float* b2 = (const float*)d_in[5];
    const float* W3 = (const float*)d_in[6];
    const float* b3 = (const float*)d_in[7];
    float* out = (float*)d_out;

    int N = in_sizes[0] / D;    // 100000
    int E = in_sizes[1] / 2;    // 1600000
    const int* srcp = ei;
    const int* dstp = ei + E;

    // workspace layout (256B aligned). deg/bsums/rank overlay the Y16 region:
    // they are dead before the first kagg writes Y16.
    char* base = (char*)d_ws;
    size_t off = 0;
    auto alloc = [&](size_t bytes) {
        char* p = base + off;
        off = (off + bytes + 255) & ~(size_t)255;
        return p;
    };
    int*      offs = (int*)alloc((size_t)(N + 1) * 4);
    float*    dinv = (float*)alloc((size_t)N * 4);
    int2*     ew   = (int2*)alloc((size_t)E * 8);
    _Float16* H    = (_Float16*)alloc((size_t)N * D * 2);
    char*     yb   = alloc((size_t)N * D * 2);            // Y16 region (25.6MB)
    _Float16* Y16  = (_Float16*)yb;
    int*      deg   = (int*)yb;                            // overlay: N*4
    int*      bsums = (int*)(yb + (size_t)N * 4);          // 256*4
    int*      rank  = (int*)(yb + (size_t)N * 4 + 4096);   // E*4
    (void)ws_size;

    hipMemsetAsync(deg, 0, (size_t)N * 4, stream);

    khist<<<dim3((E + 255) / 256), dim3(256), 0, stream>>>(dstp, deg, rank, E);
    int nb = (N + 1023) / 1024;
    kscan1<<<dim3(nb), dim3(1024), 0, stream>>>(deg, offs, bsums, dinv, N);
    kscan2<<<dim3(1), dim3(128), 0, stream>>>(bsums, nb);
    kscan3<<<dim3((N + 255) / 256), dim3(256), 0, stream>>>(offs, bsums, N, E);
    kscatter<<<dim3((E + 255) / 256), dim3(256), 0, stream>>>(srcp, dstp, rank, offs, dinv, ew, E);

    dim3 gg((N + 127) / 128), gb(512);
    dim3 a1((N + 3) / 4), a2((N + 7) / 8), ab(256);

    // layer 1: x(fp32) -> H -> Y16 (relu)
    kgemm_mfma<false><<<gg, gb, 0, stream>>>(x, W1, H, N);
    kagg1<true><<<a1, ab, 0, stream>>>((const __half*)H, ew, offs, dinv, b1, Y16, N, 1);
    // layer 2: Y16 -> H -> Y16 (relu)  [2-node/wave ILP variant]
    kgemm_mfma<true><<<gg, gb, 0, stream>>>(Y16, W2, H, N);
    kagg2<true><<<a2, ab, 0, stream>>>((const __half*)H, ew, offs, dinv, b2, Y16, N, 1);
    // layer 3: Y16 -> H -> out(fp32, no relu)
    kgemm_mfma<true><<<gg, gb, 0, stream>>>(Y16, W3, H, N);
    kagg1<false><<<a1, ab, 0, stream>>>((const __half*)H, ew, offs, dinv, b3, out, N, 0);
}